// Round 1
// baseline (186.103 us; speedup 1.0000x reference)
//
#include <hip/hip_runtime.h>

#define NB  2
#define NH  12
#define NQ  2048
#define NKV 2048
#define DH  64

typedef __attribute__((ext_vector_type(8))) short bf16x8;
typedef __attribute__((ext_vector_type(4))) float f32x4;

__device__ __forceinline__ unsigned short f2bf(float f) {
    unsigned int u = __float_as_uint(f);
    u += 0x7FFFu + ((u >> 16) & 1u);          // round-to-nearest-even
    return (unsigned short)(u >> 16);
}

__global__ __launch_bounds__(256, 3)
void attn_fwd(const float* __restrict__ Q, const float* __restrict__ K,
              const float* __restrict__ V, const float* __restrict__ M,
              const float* __restrict__ Bias, float* __restrict__ O)
{
    const int tid  = threadIdx.x;
    const int wv   = tid >> 6;      // wave 0..3, owns q-rows [wv*16, wv*16+16)
    const int lane = tid & 63;
    const int l16  = lane & 15;
    const int g    = lane >> 4;     // 4-group within wave

    const int qt = blockIdx.x & 31;            // 32 q-tiles of 64
    const int h  = (blockIdx.x >> 5) % NH;
    const int b  = blockIdx.x / (32 * NH);
    const int q0 = qt * 64;

    __shared__ float bias_s[2112];             // bias band for this (h, q-tile)
    __shared__ unsigned short Ks[32][72];      // K tile [kv][d], stride 144B (16B-aligned, 2-way)
    __shared__ unsigned short Vs[64][40];      // V^T tile [d][kv], stride 80B (16B-aligned, 2-way)
    __shared__ unsigned short Ps[4][16][32];   // per-wave P transpose buffer

    // ---- stage bias band: pos = q - k + NKV for q in [q0,q0+64), k in [0,2048)
    //      pos in [q0+1, q0+2111];  bias_s[i] = Bias[(q0+1+i)*NH + h]
    for (int i = tid; i < 2112; i += 256)
        bias_s[i] = Bias[(size_t)(q0 + 1 + i) * NH + h];

    // ---- Q fragments (A-frag: row = l16, k = g*8 + j), d split into two K=32 chunks
    const float* qptr = Q + (((size_t)b * NH + h) * NQ + q0 + wv * 16 + l16) * DH;
    bf16x8 qa[2];
#pragma unroll
    for (int dc = 0; dc < 2; ++dc) {
        const float4 f0 = *(const float4*)(qptr + dc * 32 + g * 8);
        const float4 f1 = *(const float4*)(qptr + dc * 32 + g * 8 + 4);
        qa[dc][0] = (short)f2bf(f0.x); qa[dc][1] = (short)f2bf(f0.y);
        qa[dc][2] = (short)f2bf(f0.z); qa[dc][3] = (short)f2bf(f0.w);
        qa[dc][4] = (short)f2bf(f1.x); qa[dc][5] = (short)f2bf(f1.y);
        qa[dc][6] = (short)f2bf(f1.z); qa[dc][7] = (short)f2bf(f1.w);
    }

    f32x4 o[4];
#pragma unroll
    for (int nt = 0; nt < 4; ++nt) { o[nt][0]=0.f; o[nt][1]=0.f; o[nt][2]=0.f; o[nt][3]=0.f; }
    float m_r[4] = {-1e30f, -1e30f, -1e30f, -1e30f};
    float l_r[4] = {0.f, 0.f, 0.f, 0.f};

    const float* kbase = K + ((size_t)b * NH + h) * NKV * DH;
    const float* vbase = V + ((size_t)b * NH + h) * NKV * DH;
    const float* mbase = M + ((size_t)b * NQ + q0 + wv * 16) * NKV;  // mask[b][0][q][k]

    for (int kv0 = 0; kv0 < NKV; kv0 += 32) {
        __syncthreads();   // previous iter's LDS reads done before restage
        // ---- stage K tile (32x64) as bf16, coalesced float4 reads
#pragma unroll
        for (int i = 0; i < 2; ++i) {
            const int gi = i * 256 + tid;          // 512 float4-groups
            const int r = gi >> 4, c = (gi & 15) * 4;
            const float4 f = *(const float4*)(kbase + (size_t)(kv0 + r) * DH + c);
            unsigned short* dst = &Ks[r][c];
            dst[0] = f2bf(f.x); dst[1] = f2bf(f.y); dst[2] = f2bf(f.z); dst[3] = f2bf(f.w);
        }
        // ---- stage V tile transposed (V^T[d][kv])
#pragma unroll
        for (int i = 0; i < 2; ++i) {
            const int gi = i * 256 + tid;
            const int r = gi >> 4, c = (gi & 15) * 4;
            const float4 f = *(const float4*)(vbase + (size_t)(kv0 + r) * DH + c);
            Vs[c+0][r] = f2bf(f.x); Vs[c+1][r] = f2bf(f.y);
            Vs[c+2][r] = f2bf(f.z); Vs[c+3][r] = f2bf(f.w);
        }
        __syncthreads();

        // ---- S = Q K^T : two 16x16 n-tiles, each K=64 as two K=32 MFMAs
        f32x4 s[2];
#pragma unroll
        for (int nt = 0; nt < 2; ++nt) {
            f32x4 acc; acc[0]=0.f; acc[1]=0.f; acc[2]=0.f; acc[3]=0.f;
            const bf16x8 kb0 = *(const bf16x8*)(&Ks[nt*16 + l16][g*8]);
            const bf16x8 kb1 = *(const bf16x8*)(&Ks[nt*16 + l16][32 + g*8]);
            acc = __builtin_amdgcn_mfma_f32_16x16x32_bf16(qa[0], kb0, acc, 0, 0, 0);
            acc = __builtin_amdgcn_mfma_f32_16x16x32_bf16(qa[1], kb1, acc, 0, 0, 0);
            s[nt] = acc;
        }

        // ---- scale + bias + mask, online softmax (rows = wv*16 + g*4 + r)
#pragma unroll
        for (int r = 0; r < 4; ++r) {
            const int qr = wv * 16 + g * 4 + r;    // local q row (0..63)
#pragma unroll
            for (int nt = 0; nt < 2; ++nt) {
                const int kk = kv0 + nt * 16 + l16;
                float x = s[nt][r] * 0.125f;
                x += bias_s[qr - kk + 2047];
                x += mbase[(size_t)(g * 4 + r) * NKV + kk];
                s[nt][r] = x;
            }
            float mx = fmaxf(s[0][r], s[1][r]);
            mx = fmaxf(mx, __shfl_xor(mx, 1));
            mx = fmaxf(mx, __shfl_xor(mx, 2));
            mx = fmaxf(mx, __shfl_xor(mx, 4));
            mx = fmaxf(mx, __shfl_xor(mx, 8));
            const float mo = m_r[r];
            const float mn = fmaxf(mo, mx);
            m_r[r] = mn;
            const float alpha = __expf(mo - mn);   // 0 on first tile (mo=-1e30)
            const float p0 = __expf(s[0][r] - mn);
            const float p1 = __expf(s[1][r] - mn);
            float rs = p0 + p1;
            rs += __shfl_xor(rs, 1);
            rs += __shfl_xor(rs, 2);
            rs += __shfl_xor(rs, 4);
            rs += __shfl_xor(rs, 8);
            l_r[r] = l_r[r] * alpha + rs;
#pragma unroll
            for (int nt = 0; nt < 4; ++nt) o[nt][r] *= alpha;
            // C/D layout -> LDS so we can reload P in A-frag layout
            Ps[wv][g * 4 + r][l16]      = f2bf(p0);
            Ps[wv][g * 4 + r][16 + l16] = f2bf(p1);
        }

        // ---- PV: A = P (16x32), B^T = V^T (n=d, k=kv); in-wave LDS ordering is safe
        const bf16x8 pa = *(const bf16x8*)(&Ps[wv][l16][g * 8]);
#pragma unroll
        for (int nt = 0; nt < 4; ++nt) {
            const bf16x8 vb = *(const bf16x8*)(&Vs[nt * 16 + l16][g * 8]);
            o[nt] = __builtin_amdgcn_mfma_f32_16x16x32_bf16(pa, vb, o[nt], 0, 0, 0);
        }
    }

    // ---- normalize and store (C/D layout: col = nt*16+l16, row = g*4+r)
    float* obase = O + (((size_t)b * NH + h) * NQ + q0 + wv * 16) * DH;
#pragma unroll
    for (int r = 0; r < 4; ++r) {
        const float inv = 1.f / l_r[r];
#pragma unroll
        for (int nt = 0; nt < 4; ++nt)
            obase[(size_t)(g * 4 + r) * DH + nt * 16 + l16] = o[nt][r] * inv;
    }
}

extern "C" void kernel_launch(void* const* d_in, const int* in_sizes, int n_in,
                              void* d_out, int out_size, void* d_ws, size_t ws_size,
                              hipStream_t stream) {
    const float* Q    = (const float*)d_in[0];
    const float* K    = (const float*)d_in[1];
    const float* V    = (const float*)d_in[2];
    const float* M    = (const float*)d_in[3];
    const float* Bias = (const float*)d_in[4];
    float* O = (float*)d_out;

    dim3 grid(NB * NH * (NQ / 64));   // 768 blocks = 3/CU
    dim3 block(256);
    attn_fwd<<<grid, block, 0, stream>>>(Q, K, V, M, Bias, O);
}

// Round 2
// 146.902 us; speedup vs baseline: 1.2669x; 1.2669x over previous
//
#include <hip/hip_runtime.h>

#define NB  2
#define NH  12
#define NQ  2048
#define NKV 2048
#define DH  64
#define KVB 64

typedef __attribute__((ext_vector_type(8))) short bf16x8;
typedef __attribute__((ext_vector_type(4))) float f32x4;

__device__ __forceinline__ unsigned short f2bf(float f) {
    unsigned int u = __float_as_uint(f);
    u += 0x7FFFu + ((u >> 16) & 1u);          // round-to-nearest-even
    return (unsigned short)(u >> 16);
}

__global__ __launch_bounds__(256, 3)
void attn_fwd(const float* __restrict__ Q, const float* __restrict__ K,
              const float* __restrict__ V, const float* __restrict__ M,
              const float* __restrict__ Bias, float* __restrict__ O)
{
    const int tid  = threadIdx.x;
    const int wv   = tid >> 6;      // wave 0..3, owns q-rows [wv*16, wv*16+16)
    const int lane = tid & 63;
    const int l16  = lane & 15;
    const int g    = lane >> 4;

    const int qt = blockIdx.x & 31;            // 32 q-tiles of 64
    const int h  = (blockIdx.x >> 5) % NH;
    const int b  = blockIdx.x / (32 * NH);
    const int q0 = qt * 64;

    __shared__ float bias_s[2112];             // bias band for this (h, q-tile)
    __shared__ unsigned short Ks[KVB][72];     // K tile [kv][d], stride 144B
    __shared__ unsigned short Vs[DH][72];      // V^T tile [d][kv], stride 144B
    __shared__ unsigned short Ps[4][16][72];   // per-wave P transpose buffer

    // ---- stage bias band: bias_s[i] = Bias[(q0+1+i)*NH + h]
    for (int i = tid; i < 2112; i += 256)
        bias_s[i] = Bias[(size_t)(q0 + 1 + i) * NH + h];

    // ---- Q fragments (A-frag: row = l16, k = g*8 + j), d split into two K=32 chunks
    const float* qptr = Q + (((size_t)b * NH + h) * NQ + q0 + wv * 16 + l16) * DH;
    bf16x8 qa[2];
#pragma unroll
    for (int dc = 0; dc < 2; ++dc) {
        const float4 f0 = *(const float4*)(qptr + dc * 32 + g * 8);
        const float4 f1 = *(const float4*)(qptr + dc * 32 + g * 8 + 4);
        qa[dc][0] = (short)f2bf(f0.x); qa[dc][1] = (short)f2bf(f0.y);
        qa[dc][2] = (short)f2bf(f0.z); qa[dc][3] = (short)f2bf(f0.w);
        qa[dc][4] = (short)f2bf(f1.x); qa[dc][5] = (short)f2bf(f1.y);
        qa[dc][6] = (short)f2bf(f1.z); qa[dc][7] = (short)f2bf(f1.w);
    }

    f32x4 o[4];
#pragma unroll
    for (int nt = 0; nt < 4; ++nt) { o[nt][0]=0.f; o[nt][1]=0.f; o[nt][2]=0.f; o[nt][3]=0.f; }
    float m_r[4] = {-1e30f, -1e30f, -1e30f, -1e30f};
    float l_r[4] = {0.f, 0.f, 0.f, 0.f};

    const float* kbase = K + ((size_t)b * NH + h) * NKV * DH;
    const float* vbase = V + ((size_t)b * NH + h) * NKV * DH;
    // per-lane mask row pointers: mask[b][0][q0+wv*16+g*4+r][l16 + ...]
    const float* mrow[4];
#pragma unroll
    for (int r = 0; r < 4; ++r)
        mrow[r] = M + (size_t)b * NQ * NKV
                    + (size_t)(q0 + wv * 16 + g * 4 + r) * NKV + l16;

    // staging thread mapping: 64x64 tile, thread covers rows i*16+r0, cols c0..c0+3
    const int r0 = tid >> 4, c0 = (tid & 15) * 4;

    // ---- prologue: issue tile-0 loads into registers
    float4 kr[4], vr[4];
    float  mr[4][4];
#pragma unroll
    for (int i = 0; i < 4; ++i)
        kr[i] = *(const float4*)(kbase + (size_t)(i * 16 + r0) * DH + c0);
#pragma unroll
    for (int i = 0; i < 4; ++i)
        vr[i] = *(const float4*)(vbase + (size_t)(i * 16 + r0) * DH + c0);
#pragma unroll
    for (int r = 0; r < 4; ++r)
#pragma unroll
        for (int nt = 0; nt < 4; ++nt) mr[r][nt] = mrow[r][nt * 16];

    for (int t = 0; t < NKV / KVB; ++t) {
        const int kv0 = t * KVB;
        const int kvn = ((t + 1) & (NKV / KVB - 1)) * KVB;  // wraps on last iter (harmless reload)

        __syncthreads();   // all waves done computing on previous LDS tile
        // ---- write staged registers -> LDS (convert to bf16)
#pragma unroll
        for (int i = 0; i < 4; ++i) {
            unsigned short* dst = &Ks[i * 16 + r0][c0];
            dst[0] = f2bf(kr[i].x); dst[1] = f2bf(kr[i].y);
            dst[2] = f2bf(kr[i].z); dst[3] = f2bf(kr[i].w);
        }
#pragma unroll
        for (int i = 0; i < 4; ++i) {
            const int rr = i * 16 + r0;
            Vs[c0 + 0][rr] = f2bf(vr[i].x); Vs[c0 + 1][rr] = f2bf(vr[i].y);
            Vs[c0 + 2][rr] = f2bf(vr[i].z); Vs[c0 + 3][rr] = f2bf(vr[i].w);
        }
        // ---- issue next-tile K/V loads (latency hides under compute below)
#pragma unroll
        for (int i = 0; i < 4; ++i)
            kr[i] = *(const float4*)(kbase + (size_t)(kvn + i * 16 + r0) * DH + c0);
#pragma unroll
        for (int i = 0; i < 4; ++i)
            vr[i] = *(const float4*)(vbase + (size_t)(kvn + i * 16 + r0) * DH + c0);
        __syncthreads();   // LDS tile ready

        // ---- S = Q K^T : four 16-wide n-tiles, K=64 as two K=32 MFMAs each
        f32x4 s[4];
#pragma unroll
        for (int nt = 0; nt < 4; ++nt) {
            f32x4 acc; acc[0]=0.f; acc[1]=0.f; acc[2]=0.f; acc[3]=0.f;
            const bf16x8 kb0 = *(const bf16x8*)(&Ks[nt * 16 + l16][g * 8]);
            const bf16x8 kb1 = *(const bf16x8*)(&Ks[nt * 16 + l16][32 + g * 8]);
            acc = __builtin_amdgcn_mfma_f32_16x16x32_bf16(qa[0], kb0, acc, 0, 0, 0);
            acc = __builtin_amdgcn_mfma_f32_16x16x32_bf16(qa[1], kb1, acc, 0, 0, 0);
            s[nt] = acc;
        }

        // ---- scale + bias + mask, online softmax (row = wv*16 + g*4 + r)
#pragma unroll
        for (int r = 0; r < 4; ++r) {
            const int qr = wv * 16 + g * 4 + r;
#pragma unroll
            for (int nt = 0; nt < 4; ++nt) {
                float x = s[nt][r] * 0.125f + mr[r][nt];
                x += bias_s[qr - (kv0 + nt * 16 + l16) + 2047];
                s[nt][r] = x;
            }
            float mx = fmaxf(fmaxf(s[0][r], s[1][r]), fmaxf(s[2][r], s[3][r]));
            mx = fmaxf(mx, __shfl_xor(mx, 1));
            mx = fmaxf(mx, __shfl_xor(mx, 2));
            mx = fmaxf(mx, __shfl_xor(mx, 4));
            mx = fmaxf(mx, __shfl_xor(mx, 8));
            const float mo = m_r[r];
            const float mn = fmaxf(mo, mx);
            m_r[r] = mn;
            const float alpha = __expf(mo - mn);
            float p[4], rs = 0.f;
#pragma unroll
            for (int nt = 0; nt < 4; ++nt) { p[nt] = __expf(s[nt][r] - mn); rs += p[nt]; }
            rs += __shfl_xor(rs, 1);
            rs += __shfl_xor(rs, 2);
            rs += __shfl_xor(rs, 4);
            rs += __shfl_xor(rs, 8);
            l_r[r] = l_r[r] * alpha + rs;
#pragma unroll
            for (int nt = 0; nt < 4; ++nt) o[nt][r] *= alpha;
#pragma unroll
            for (int nt = 0; nt < 4; ++nt)
                Ps[wv][g * 4 + r][nt * 16 + l16] = f2bf(p[nt]);
        }

        // ---- issue next-tile mask loads (mr consumed above; hides under PV + next stage)
#pragma unroll
        for (int r = 0; r < 4; ++r)
#pragma unroll
            for (int nt = 0; nt < 4; ++nt) mr[r][nt] = mrow[r][kvn + nt * 16];

        // ---- PV: A = P (16x64), B^T = V^T; two K=32 chunks; in-wave Ps RAW is in-order
#pragma unroll
        for (int kc = 0; kc < 2; ++kc) {
            const bf16x8 pa = *(const bf16x8*)(&Ps[wv][l16][kc * 32 + g * 8]);
#pragma unroll
            for (int nt = 0; nt < 4; ++nt) {
                const bf16x8 vb = *(const bf16x8*)(&Vs[nt * 16 + l16][kc * 32 + g * 8]);
                o[nt] = __builtin_amdgcn_mfma_f32_16x16x32_bf16(pa, vb, o[nt], 0, 0, 0);
            }
        }
    }

    // ---- normalize and store (C/D layout: col = nt*16+l16, row = g*4+r)
    float* obase = O + (((size_t)b * NH + h) * NQ + q0 + wv * 16) * DH;
#pragma unroll
    for (int r = 0; r < 4; ++r) {
        const float inv = 1.f / l_r[r];
#pragma unroll
        for (int nt = 0; nt < 4; ++nt)
            obase[(size_t)(g * 4 + r) * DH + nt * 16 + l16] = o[nt][r] * inv;
    }
}

extern "C" void kernel_launch(void* const* d_in, const int* in_sizes, int n_in,
                              void* d_out, int out_size, void* d_ws, size_t ws_size,
                              hipStream_t stream) {
    const float* Q    = (const float*)d_in[0];
    const float* K    = (const float*)d_in[1];
    const float* V    = (const float*)d_in[2];
    const float* M    = (const float*)d_in[3];
    const float* Bias = (const float*)d_in[4];
    float* O = (float*)d_out;

    dim3 grid(NB * NH * (NQ / 64));   // 768 blocks = 3/CU
    dim3 block(256);
    attn_fwd<<<grid, block, 0, stream>>>(Q, K, V, M, Bias, O);
}